// Round 1
// baseline (870.703 us; speedup 1.0000x reference)
//
#include <hip/hip_runtime.h>
#include <cstddef>

typedef unsigned short u16;
typedef __attribute__((ext_vector_type(8))) short bf16x8;   // 8 bf16 in 4 VGPRs
typedef __attribute__((ext_vector_type(4))) float f32x4;

__device__ __forceinline__ u16 f2bf(float f) {
  union { float f; unsigned u; } x; x.f = f;
  unsigned r = x.u + 0x7fffu + ((x.u >> 16) & 1u);   // RNE; inputs are finite
  return (u16)(r >> 16);
}
__device__ __forceinline__ float bf2f(u16 h) {
  union { unsigned u; float f; } x; x.u = ((unsigned)h) << 16;
  return x.f;
}

// async global->LDS, 16 B per lane; LDS dest is wave-uniform base + lane*16
__device__ __forceinline__ void gll16(const u16* g, u16* ldsbase) {
  __builtin_amdgcn_global_load_lds(
      (const __attribute__((address_space(1))) void*)g,
      (__attribute__((address_space(3))) void*)ldsbase, 16, 0, 0);
}

// ---------------------------------------------------------------------------
__global__ __launch_bounds__(256) void f32_to_bf16(const float* __restrict__ in,
                                                   u16* __restrict__ out, size_t n) {
  size_t i = (size_t)blockIdx.x * 256 + threadIdx.x;
  if (i < n) out[i] = f2bf(in[i]);
}

// transpose f32 [R][C] -> bf16 [C][R]   (R,C multiples of 32) grid(C/32, R/32)
__global__ __launch_bounds__(256) void transpose_f32_bf16(const float* __restrict__ in,
                                                          u16* __restrict__ out,
                                                          int R, int C) {
  __shared__ float tile[32][33];
  int c0 = blockIdx.x * 32, r0 = blockIdx.y * 32;
  int tx = threadIdx.x & 31, ty = threadIdx.x >> 5;   // ty: 0..7
  #pragma unroll
  for (int i = ty; i < 32; i += 8)
    tile[i][tx] = in[(size_t)(r0 + i) * C + c0 + tx];
  __syncthreads();
  #pragma unroll
  for (int i = ty; i < 32; i += 8)
    out[(size_t)(c0 + i) * R + r0 + tx] = f2bf(tile[tx][i]);
}

// ---------------------------------------------------------------------------
// 256x256-tile 8-phase GEMM: C[z][M][N] = A[z][M][K] @ Bt[z][N][K]^T
// bf16 in, fp32 accum. BK=64, 512 threads = 8 waves (2Mx4N), wave tile 128x64.
// T2: granule XOR-swizzle (pre-swizzled global source, linear LDS dest,
//     swizzled ds_read_b128) -> conflict-free fragment reads.
// T3/T4: half-tile staging (2 x global_load_lds each), one half per phase,
//     raw s_barrier (no drain), counted s_waitcnt vmcnt(6) once per K-tile.
// T5: s_setprio(1) around each 16-MFMA cluster.
// Overwrite-safety (stage order B-lo,B-hi,A-lo,A-hi -> region s_i of buf b
// re-staged for tile t+2 at phase i+2 of tile t): every reader finishes that
// region's ds_reads (lgkmcnt(0) + phase-end barrier) at least one phase
// before the overwriting stage is issued.
// ---------------------------------------------------------------------------
enum { EPI_F32 = 0, EPI_BF16 = 1, EPI_BF16_SCALE = 2,
       EPI_BIAS_RELU_BF16 = 3, EPI_BIAS_F32 = 4 };
enum { MODE_FULL = 0, MODE_TRI = 1, MODE_CAUSAL_K = 2 };

template <int EPI, int MODE>
__global__ __launch_bounds__(512) void gemm256(
    const u16* __restrict__ A, const u16* __restrict__ Bt,
    void* __restrict__ C0, const float* __restrict__ bias,
    int K, int lda, int ldb, int ldc,
    long long sA, long long sB, long long sC)
{
  __shared__ __align__(16) u16 lA[2][256 * 64];   // 64 KB
  __shared__ __align__(16) u16 lB[2][256 * 64];   // 64 KB

  // ---- block -> (z, mi, ni), XCD-compact swizzle (all grids %8==0) ----
  const unsigned gx = gridDim.x, gxy = gridDim.x * gridDim.y;
  unsigned id = blockIdx.x + gx * blockIdx.y + gxy * blockIdx.z;
  const unsigned nb = gxy * gridDim.z;
  unsigned p = id;
  if ((nb & 7u) == 0u) p = (id & 7u) * (nb >> 3) + (id >> 3);
  int z, mi, ni;
  if constexpr (MODE == MODE_TRI) {
    z = (int)(p / gxy);                 // gxy == tri blocks per batch
    int r = (int)(p % gxy);
    int m = 0;
    while ((m + 1) * (m + 2) / 2 <= r) m++;
    mi = m; ni = r - m * (m + 1) / 2;   // mi >= ni (lower triangle)
  } else {
    z = (int)(p / gxy);
    const unsigned rem = p % gxy;
    mi = (int)(rem / gx);
    ni = (int)(rem % gx);
  }
  const int m0 = mi * 256, n0 = ni * 256;

  A  += (long long)z * sA;
  Bt += (long long)z * sB;

  int NT = K >> 6;
  if constexpr (MODE == MODE_CAUSAL_K) NT = (m0 + 256) >> 6;  // P==0 above diag

  const int t    = threadIdx.x;
  const int lane = t & 63;
  const int wave = t >> 6;
  const int wr   = wave >> 2;          // 0..1 : owns rows wr*128..+128
  const int wc   = wave & 3;           // 0..3 : owns cols wc*64..+64
  const int quad = lane >> 4;
  const int lrow = lane & 15;

  // ---- staging addressing: pre-swizzled global source, linear LDS dest ----
  const int srow = lane >> 3;                    // 0..7 (== row & 7)
  const int scol = ((lane & 7) ^ srow) * 8;      // source granule for phys lane&7
  const u16* gAp = A  + (size_t)(m0 + wave * 8 + srow) * lda + scol;
  const u16* gBp = Bt + (size_t)(n0 + wave * 8 + srow) * ldb + scol;
  const size_t a64 = (size_t)64 * lda, b64 = (size_t)64 * ldb;
  const int lw = wave * 512;           // wave's write base within a 64-row block

  // ---- fragment read addressing (swizzled): phys granule = need ^ (row&7) ----
  const int pg0 = (quad ^ (lrow & 7)) * 8;       // ks=0
  const int pg1 = pg0 ^ 32;                      // ks=1 : (quad+4)^(lrow&7)
  const int rA = (wr * 128 + lrow) * 64;
  const int rB = (wc * 64 + lrow) * 64;

  f32x4 acc[8][4];
  const f32x4 zero = {0.f, 0.f, 0.f, 0.f};
  #pragma unroll
  for (int i = 0; i < 8; i++)
    #pragma unroll
    for (int j = 0; j < 4; j++) acc[i][j] = zero;

  // stage one half-tile (2 x gll16): s 0=B-lo 1=B-hi 2=A-lo 3=A-hi
  auto stage = [&](int b, int s, int kt) {
    const int k = kt * 64;
    if (s == 0) {
      gll16(gBp + k,            &lB[b][lw]);
      gll16(gBp + k + b64,      &lB[b][4096 + lw]);
    } else if (s == 1) {
      gll16(gBp + k + 2 * b64,  &lB[b][8192 + lw]);
      gll16(gBp + k + 3 * b64,  &lB[b][12288 + lw]);
    } else if (s == 2) {
      gll16(gAp + k,            &lA[b][lw]);
      gll16(gAp + k + a64,      &lA[b][4096 + lw]);
    } else {
      gll16(gAp + k + 2 * a64,  &lA[b][8192 + lw]);
      gll16(gAp + k + 3 * a64,  &lA[b][12288 + lw]);
    }
  };

  // ---- prologue: tile0 fully + tile1 s0..s2 -> 3 half-tiles stay in flight ----
  stage(0, 0, 0); stage(0, 1, 0); stage(0, 2, 0); stage(0, 3, 0);
  if (NT > 1) {
    stage(1, 0, 1); stage(1, 1, 1); stage(1, 2, 1);
    asm volatile("s_waitcnt vmcnt(6)" ::: "memory");   // tile0's 8 loads landed
  } else {
    asm volatile("s_waitcnt vmcnt(0)" ::: "memory");
  }
  __builtin_amdgcn_s_barrier();

  bf16x8 af[4][2], bfr[4][2];

  for (int kt = 0; kt < NT; ++kt) {
    const int bsel = kt & 1;
    const u16* sa = &lA[bsel][0];
    const u16* sb = &lB[bsel][0];

    // ---------------- phase 1 : Q(0,0)  (A h0 + B[all|lo] reads) ----------------
    #pragma unroll
    for (int mf = 0; mf < 4; ++mf) {
      af[mf][0] = *(const bf16x8*)(sa + rA + mf * 1024 + pg0);
      af[mf][1] = *(const bf16x8*)(sa + rA + mf * 1024 + pg1);
    }
    if (wc < 2) {            // whole B in B-lo: must finish before its re-stage (ph2)
      #pragma unroll
      for (int nf = 0; nf < 4; ++nf) {
        bfr[nf][0] = *(const bf16x8*)(sb + rB + nf * 1024 + pg0);
        bfr[nf][1] = *(const bf16x8*)(sb + rB + nf * 1024 + pg1);
      }
    } else {
      #pragma unroll
      for (int nf = 0; nf < 2; ++nf) {
        bfr[nf][0] = *(const bf16x8*)(sb + rB + nf * 1024 + pg0);
        bfr[nf][1] = *(const bf16x8*)(sb + rB + nf * 1024 + pg1);
      }
    }
    if (kt + 1 < NT) stage(bsel ^ 1, 3, kt + 1);
    __builtin_amdgcn_s_barrier();
    asm volatile("s_waitcnt lgkmcnt(0)" ::: "memory");
    __builtin_amdgcn_sched_barrier(0);
    __builtin_amdgcn_s_setprio(1);
    #pragma unroll
    for (int mf = 0; mf < 4; ++mf)
      #pragma unroll
      for (int nf = 0; nf < 2; ++nf) {
        acc[mf][nf] = __builtin_amdgcn_mfma_f32_16x16x32_bf16(bfr[nf][0], af[mf][0], acc[mf][nf], 0, 0, 0);
        acc[mf][nf] = __builtin_amdgcn_mfma_f32_16x16x32_bf16(bfr[nf][1], af[mf][1], acc[mf][nf], 0, 0, 0);
      }
    __builtin_amdgcn_s_setprio(0);
    __builtin_amdgcn_s_barrier();

    // ---------------- phase 2 : Q(0,1)  (B-hi reads for wc>=2) ----------------
    if (wc >= 2) {
      #pragma unroll
      for (int nf = 2; nf < 4; ++nf) {
        bfr[nf][0] = *(const bf16x8*)(sb + rB + nf * 1024 + pg0);
        bfr[nf][1] = *(const bf16x8*)(sb + rB + nf * 1024 + pg1);
      }
    }
    if (kt + 2 < NT) stage(bsel, 0, kt + 2);
    __builtin_amdgcn_s_barrier();
    asm volatile("s_waitcnt lgkmcnt(0)" ::: "memory");
    __builtin_amdgcn_sched_barrier(0);
    __builtin_amdgcn_s_setprio(1);
    #pragma unroll
    for (int mf = 0; mf < 4; ++mf)
      #pragma unroll
      for (int nf = 2; nf < 4; ++nf) {
        acc[mf][nf] = __builtin_amdgcn_mfma_f32_16x16x32_bf16(bfr[nf][0], af[mf][0], acc[mf][nf], 0, 0, 0);
        acc[mf][nf] = __builtin_amdgcn_mfma_f32_16x16x32_bf16(bfr[nf][1], af[mf][1], acc[mf][nf], 0, 0, 0);
      }
    __builtin_amdgcn_s_setprio(0);
    __builtin_amdgcn_s_barrier();

    // ---------------- phase 3 : Q(1,1)  (A h1 reads, reuse af regs) ----------------
    #pragma unroll
    for (int mf = 0; mf < 4; ++mf) {
      af[mf][0] = *(const bf16x8*)(sa + rA + (mf + 4) * 1024 + pg0);
      af[mf][1] = *(const bf16x8*)(sa + rA + (mf + 4) * 1024 + pg1);
    }
    if (kt + 2 < NT) stage(bsel, 1, kt + 2);
    __builtin_amdgcn_s_barrier();
    asm volatile("s_waitcnt lgkmcnt(0)" ::: "memory");
    __builtin_amdgcn_sched_barrier(0);
    __builtin_amdgcn_s_setprio(1);
    #pragma unroll
    for (int mf = 0; mf < 4; ++mf)
      #pragma unroll
      for (int nf = 2; nf < 4; ++nf) {
        acc[mf + 4][nf] = __builtin_amdgcn_mfma_f32_16x16x32_bf16(bfr[nf][0], af[mf][0], acc[mf + 4][nf], 0, 0, 0);
        acc[mf + 4][nf] = __builtin_amdgcn_mfma_f32_16x16x32_bf16(bfr[nf][1], af[mf][1], acc[mf + 4][nf], 0, 0, 0);
      }
    __builtin_amdgcn_s_setprio(0);
    __builtin_amdgcn_s_barrier();

    // ---------------- phase 4 : Q(1,0)  (no reads; counted vmcnt) ----------------
    if (kt + 2 < NT) {
      stage(bsel, 2, kt + 2);
      asm volatile("s_waitcnt vmcnt(6)" ::: "memory");   // tile kt+1 fully landed
    } else if (kt + 1 < NT) {
      asm volatile("s_waitcnt vmcnt(0)" ::: "memory");   // tail: drain
    }
    __builtin_amdgcn_s_barrier();
    __builtin_amdgcn_s_setprio(1);
    #pragma unroll
    for (int mf = 0; mf < 4; ++mf)
      #pragma unroll
      for (int nf = 0; nf < 2; ++nf) {
        acc[mf + 4][nf] = __builtin_amdgcn_mfma_f32_16x16x32_bf16(bfr[nf][0], af[mf][0], acc[mf + 4][nf], 0, 0, 0);
        acc[mf + 4][nf] = __builtin_amdgcn_mfma_f32_16x16x32_bf16(bfr[nf][1], af[mf][1], acc[mf + 4][nf], 0, 0, 0);
      }
    __builtin_amdgcn_s_setprio(0);
    __builtin_amdgcn_s_barrier();
  }

  // ---- epilogue: swapped C/D layout -> lane holds 4 consecutive n ----
  const size_t zoff = (size_t)((long long)z * sC);
  #pragma unroll
  for (int mf = 0; mf < 8; ++mf) {
    #pragma unroll
    for (int nf = 0; nf < 4; ++nf) {
      const size_t m  = (size_t)(m0 + wr * 128 + mf * 16 + lrow);
      const size_t nc = (size_t)(n0 + wc * 64 + nf * 16 + quad * 4);
      const size_t idx = zoff + m * (size_t)ldc + nc;
      f32x4 v = acc[mf][nf];
      if constexpr (EPI == EPI_F32) {
        *(float4*)((float*)C0 + idx) = make_float4(v[0], v[1], v[2], v[3]);
      } else if constexpr (EPI == EPI_BF16) {
        ushort4 o; o.x = f2bf(v[0]); o.y = f2bf(v[1]); o.z = f2bf(v[2]); o.w = f2bf(v[3]);
        *(ushort4*)((u16*)C0 + idx) = o;
      } else if constexpr (EPI == EPI_BF16_SCALE) {
        ushort4 o;
        o.x = f2bf(v[0] * 0.03125f); o.y = f2bf(v[1] * 0.03125f);
        o.z = f2bf(v[2] * 0.03125f); o.w = f2bf(v[3] * 0.03125f);
        *(ushort4*)((u16*)C0 + idx) = o;
      } else if constexpr (EPI == EPI_BIAS_RELU_BF16) {
        const float4 bb = *(const float4*)(bias + nc);
        float y0 = v[0] + bb.x, y1 = v[1] + bb.y, y2 = v[2] + bb.z, y3 = v[3] + bb.w;
        ushort4 o;
        o.x = f2bf(y0 > 0.f ? y0 : 0.f); o.y = f2bf(y1 > 0.f ? y1 : 0.f);
        o.z = f2bf(y2 > 0.f ? y2 : 0.f); o.w = f2bf(y3 > 0.f ? y3 : 0.f);
        *(ushort4*)((u16*)C0 + idx) = o;
      } else {  // EPI_BIAS_F32
        const float4 bb = *(const float4*)(bias + nc);
        *(float4*)((float*)C0 + idx) =
            make_float4(v[0] + bb.x, v[1] + bb.y, v[2] + bb.z, v[3] + bb.w);
      }
    }
  }
}

// ---------------------------------------------------------------------------
// in-place row softmax on bf16 scores (already scaled); cols == 2048
// ---------------------------------------------------------------------------
__global__ __launch_bounds__(256) void softmax_bf16(u16* __restrict__ SP, int causal) {
  __shared__ float red[8];
  const int row = blockIdx.x;
  const int q = row & 2047;
  u16* p = SP + (size_t)row * 2048;
  const int t = threadIdx.x;
  const int base = t * 8;
  const int limit = causal ? (q + 1) : 2048;

  uint4 raw = *(const uint4*)(p + base);
  unsigned w[4] = {raw.x, raw.y, raw.z, raw.w};
  float v[8];
  #pragma unroll
  for (int j = 0; j < 4; j++) {
    union { unsigned u; float f; } lo, hi;
    lo.u = w[j] << 16; hi.u = w[j] & 0xffff0000u;
    v[2 * j] = lo.f; v[2 * j + 1] = hi.f;
  }
  #pragma unroll
  for (int j = 0; j < 8; j++) if (base + j >= limit) v[j] = -3.4e38f;

  float mx = v[0];
  #pragma unroll
  for (int j = 1; j < 8; j++) mx = fmaxf(mx, v[j]);
  #pragma unroll
  for (int o = 32; o > 0; o >>= 1) mx = fmaxf(mx, __shfl_down(mx, o));
  if ((t & 63) == 0) red[t >> 6] = mx;
  __syncthreads();
  mx = fmaxf(fmaxf(red[0], red[1]), fmaxf(red[2], red[3]));

  float s = 0.f;
  #pragma unroll
  for (int j = 0; j < 8; j++) { float e = __expf(v[j] - mx); v[j] = e; s += e; }
  #pragma unroll
  for (int o = 32; o > 0; o >>= 1) s += __shfl_down(s, o);
  if ((t & 63) == 0) red[4 + (t >> 6)] = s;
  __syncthreads();
  const float inv = 1.f / (red[4] + red[5] + red[6] + red[7]);

  unsigned o4[4];
  #pragma unroll
  for (int j = 0; j < 4; j++)
    o4[j] = (unsigned)f2bf(v[2 * j] * inv) | ((unsigned)f2bf(v[2 * j + 1] * inv) << 16);
  *(uint4*)(p + base) = make_uint4(o4[0], o4[1], o4[2], o4[3]);
}

// ---------------------------------------------------------------------------
// LN(a + b) * g + be ; D == 1024; a bf16 (ABF=1) or f32 (ABF=0)
// ---------------------------------------------------------------------------
template <int ABF>
__global__ __launch_bounds__(256) void ln_residual(const void* __restrict__ a_,
                                                   const float* __restrict__ b,
                                                   const float* __restrict__ g,
                                                   const float* __restrict__ be,
                                                   float* __restrict__ outf,
                                                   u16* __restrict__ outb) {
  __shared__ float red[8];
  const size_t base = (size_t)blockIdx.x * 1024;
  const int t = threadIdx.x;
  const int i0 = t * 4;

  float va[4];
  if constexpr (ABF) {
    const ushort4 h = *(const ushort4*)((const u16*)a_ + base + i0);
    va[0] = bf2f(h.x); va[1] = bf2f(h.y); va[2] = bf2f(h.z); va[3] = bf2f(h.w);
  } else {
    const float4 f = *(const float4*)((const float*)a_ + base + i0);
    va[0] = f.x; va[1] = f.y; va[2] = f.z; va[3] = f.w;
  }
  const float4 vb = *(const float4*)(b + base + i0);
  float v[4] = {va[0] + vb.x, va[1] + vb.y, va[2] + vb.z, va[3] + vb.w};

  float s = v[0] + v[1] + v[2] + v[3];
  #pragma unroll
  for (int o = 32; o > 0; o >>= 1) s += __shfl_down(s, o);
  if ((t & 63) == 0) red[t >> 6] = s;
  __syncthreads();
  const float mean = (red[0] + red[1] + red[2] + red[3]) * (1.f / 1024.f);

  float qq = 0.f;
  #pragma unroll
  for (int i = 0; i < 4; i++) { float d = v[i] - mean; qq += d * d; }
  #pragma unroll
  for (int o = 32; o > 0; o >>= 1) qq += __shfl_down(qq, o);
  if ((t & 63) == 0) red[4 + (t >> 6)] = qq;
  __syncthreads();
  const float rstd = rsqrtf((red[4] + red[5] + red[6] + red[7]) * (1.f / 1024.f) + 1e-5f);

  const float4 gg = *(const float4*)(g + i0);
  const float4 bb = *(const float4*)(be + i0);
  float y0 = (v[0] - mean) * rstd * gg.x + bb.x;
  float y1 = (v[1] - mean) * rstd * gg.y + bb.y;
  float y2 = (v[2] - mean) * rstd * gg.z + bb.z;
  float y3 = (v[3] - mean) * rstd * gg.w + bb.w;
  if (outf) *(float4*)(outf + base + i0) = make_float4(y0, y1, y2, y3);
  if (outb) {
    ushort4 o4; o4.x = f2bf(y0); o4.y = f2bf(y1); o4.z = f2bf(y2); o4.w = f2bf(y3);
    *(ushort4*)(outb + base + i0) = o4;
  }
}

// ---------------------------------------------------------------------------
extern "C" void kernel_launch(void* const* d_in, const int* in_sizes, int n_in,
                              void* d_out, int out_size, void* d_ws, size_t ws_size,
                              hipStream_t stream)
{
  const float* y_in = (const float*)d_in[0];
  const float* Z_in = (const float*)d_in[1];
  const float* WQ1  = (const float*)d_in[2];
  const float* WK1  = (const float*)d_in[3];
  const float* WV1  = (const float*)d_in[4];
  const float* WQ2  = (const float*)d_in[5];
  const float* WK2  = (const float*)d_in[6];
  const float* WV2  = (const float*)d_in[7];
  const float* Wff1 = (const float*)d_in[8];
  const float* bff1 = (const float*)d_in[9];
  const float* Wff2 = (const float*)d_in[10];
  const float* bff2 = (const float*)d_in[11];
  const float* g1  = (const float*)d_in[12];
  const float* be1 = (const float*)d_in[13];
  const float* g2  = (const float*)d_in[14];
  const float* be2 = (const float*)d_in[15];
  const float* g3  = (const float*)d_in[16];
  const float* be3 = (const float*)d_in[17];
  (void)in_sizes; (void)n_in; (void)out_size;

  constexpr int Bn = 4, S = 2048, D = 1024, DF = 4096;
  constexpr long long BS = (long long)Bn * S;  // 8192 rows
  const long long SD = (long long)S * D;                 // 2M
  const long long SS = (long long)S * S;                 // 4M
  const long long SD2 = (long long)S * 2 * D;            // 4M: QKb batch stride

  char* ws = (char*)d_ws;
  size_t off = 0;
  auto alloc = [&](size_t bytes) -> char* {
    char* p = ws + off;
    off += (bytes + 255) & ~(size_t)255;
    return p;
  };

  // ---- workspace. NOTE: wq1t..wk1t must stay contiguous (merged Q|K weight
  // view for stage 1) — sizes are multiples of 256 B.
  u16* wq1t  = (u16*)alloc((size_t)D * D * 2);
  u16* wk1t  = (u16*)alloc((size_t)D * D * 2);
  u16* wv1t  = (u16*)alloc((size_t)D * D * 2);
  u16* wq2t  = (u16*)alloc((size_t)D * D * 2);
  u16* wk2t  = (u16*)alloc((size_t)D * D * 2);
  u16* wv2t  = (u16*)alloc((size_t)D * D * 2);
  u16* wff1t = (u16*)alloc((size_t)D * DF * 2);   // [4096][1024]
  u16* wff2t = (u16*)alloc((size_t)D * DF * 2);   // [1024][4096]
  u16* ybf   = (u16*)alloc((size_t)BS * D * 2);   // X1; reused as y1b after LN1
  u16* zbf   = (u16*)alloc((size_t)BS * D * 2);   // Z;  reused as y2b after LN2
  u16* QKb   = (u16*)alloc((size_t)BS * 2 * D * 2); // [8192][2048]: Q | K
  u16* Vtb   = (u16*)alloc((size_t)D * BS * 2);   // [1024][8192]: V^T, batch = col window
  u16* SPb   = (u16*)alloc((size_t)Bn * S * S * 2); // scores/probs bf16, in-place
  float* attnF = (float*)alloc((size_t)BS * D * 4); // attn out f32; reused as F
  u16*   y1b = ybf;
  u16*   y2b = zbf;
  u16*   Hb  = QKb;      // stage-3 hidden [8192][4096] overlays QKb|Vtb|SPb (dead)
  float* Fb  = attnF;

  if (off > ws_size) return;   // fail cleanly (absmax) instead of GPU fault

  const dim3 blk(256);
  const dim3 blk512(512);

  // ---- input converts + weight transposes ----
  f32_to_bf16<<<dim3((unsigned)((BS * D) / 256)), blk, 0, stream>>>(y_in, ybf, (size_t)BS * D);
  f32_to_bf16<<<dim3((unsigned)((BS * D) / 256)), blk, 0, stream>>>(Z_in, zbf, (size_t)BS * D);
  transpose_f32_bf16<<<dim3(D / 32, D / 32), blk, 0, stream>>>(WQ1, wq1t, D, D);
  transpose_f32_bf16<<<dim3(D / 32, D / 32), blk, 0, stream>>>(WK1, wk1t, D, D);
  transpose_f32_bf16<<<dim3(D / 32, D / 32), blk, 0, stream>>>(WV1, wv1t, D, D);
  transpose_f32_bf16<<<dim3(D / 32, D / 32), blk, 0, stream>>>(WQ2, wq2t, D, D);
  transpose_f32_bf16<<<dim3(D / 32, D / 32), blk, 0, stream>>>(WK2, wk2t, D, D);
  transpose_f32_bf16<<<dim3(D / 32, D / 32), blk, 0, stream>>>(WV2, wv2t, D, D);
  transpose_f32_bf16<<<dim3(DF / 32, D / 32), blk, 0, stream>>>(Wff1, wff1t, D, DF);
  transpose_f32_bf16<<<dim3(D / 32, DF / 32), blk, 0, stream>>>(Wff2, wff2t, DF, D);

  // ---- stage 1: causal self-attention + add&norm ----
  // Q|K projection: merged WQ^T||WK^T view (contiguous), C = QKb [8192][2048]
  gemm256<EPI_BF16, MODE_FULL><<<dim3(2 * D / 256, BS / 256, 1), blk512, 0, stream>>>(
      ybf, wq1t, QKb, nullptr, D, D, D, 2 * D, 0, 0, 0);
  // V^T: Vt[d][s] = sum_k WvT[d][k] * X[s][k]  -> C [1024][8192]
  gemm256<EPI_BF16, MODE_FULL><<<dim3((unsigned)(BS / 256), D / 256, 1), blk512, 0, stream>>>(
      wv1t, ybf, Vtb, nullptr, D, D, D, (int)BS, 0, 0, 0);
  // causal scores: only lower-triangle tiles (36 of 64 per batch)
  gemm256<EPI_BF16_SCALE, MODE_TRI><<<dim3(36, 1, Bn), blk512, 0, stream>>>(
      QKb, QKb + D, SPb, nullptr, D, 2 * D, 2 * D, S, SD2, SD2, SS);
  softmax_bf16<<<dim3((unsigned)(Bn * S)), blk, 0, stream>>>(SPb, 1);
  // PV: K-loop clamped to diagonal (P == 0 above it)
  gemm256<EPI_F32, MODE_CAUSAL_K><<<dim3(D / 256, S / 256, Bn), blk512, 0, stream>>>(
      SPb, Vtb, attnF, nullptr, S, S, (int)BS, D, SS, S, SD);
  ln_residual<0><<<dim3((unsigned)BS), blk, 0, stream>>>(y_in, attnF, g1, be1, nullptr, y1b);

  // ---- stage 2: cross-attention + add&norm ----
  gemm256<EPI_BF16, MODE_FULL><<<dim3(D / 256, BS / 256, 1), blk512, 0, stream>>>(
      y1b, wq2t, QKb, nullptr, D, D, D, 2 * D, 0, 0, 0);
  gemm256<EPI_BF16, MODE_FULL><<<dim3(D / 256, BS / 256, 1), blk512, 0, stream>>>(
      zbf, wk2t, QKb + D, nullptr, D, D, D, 2 * D, 0, 0, 0);
  gemm256<EPI_BF16, MODE_FULL><<<dim3((unsigned)(BS / 256), D / 256, 1), blk512, 0, stream>>>(
      wv2t, zbf, Vtb, nullptr, D, D, D, (int)BS, 0, 0, 0);
  gemm256<EPI_BF16_SCALE, MODE_FULL><<<dim3(S / 256, S / 256, Bn), blk512, 0, stream>>>(
      QKb, QKb + D, SPb, nullptr, D, 2 * D, 2 * D, S, SD2, SD2, SS);
  softmax_bf16<<<dim3((unsigned)(Bn * S)), blk, 0, stream>>>(SPb, 0);
  gemm256<EPI_F32, MODE_FULL><<<dim3(D / 256, S / 256, Bn), blk512, 0, stream>>>(
      SPb, Vtb, attnF, nullptr, S, S, (int)BS, D, SS, S, SD);
  ln_residual<1><<<dim3((unsigned)BS), blk, 0, stream>>>(y1b, attnF, g2, be2, nullptr, y2b);

  // ---- stage 3: FFN + add&norm ----
  gemm256<EPI_BIAS_RELU_BF16, MODE_FULL><<<dim3(DF / 256, BS / 256, 1), blk512, 0, stream>>>(
      y2b, wff1t, Hb, bff1, D, D, D, DF, 0, 0, 0);
  gemm256<EPI_BIAS_F32, MODE_FULL><<<dim3(D / 256, BS / 256, 1), blk512, 0, stream>>>(
      Hb, wff2t, Fb, bff2, DF, DF, DF, D, 0, 0, 0);
  ln_residual<1><<<dim3((unsigned)BS), blk, 0, stream>>>(y2b, Fb, g3, be3, (float*)d_out, nullptr);
}

// Round 2
// 740.622 us; speedup vs baseline: 1.1756x; 1.1756x over previous
//
#include <hip/hip_runtime.h>
#include <cstddef>

typedef unsigned short u16;
typedef __attribute__((ext_vector_type(8))) short bf16x8;   // 8 bf16 in 4 VGPRs
typedef __attribute__((ext_vector_type(4))) float f32x4;

__device__ __forceinline__ u16 f2bf(float f) {
  union { float f; unsigned u; } x; x.f = f;
  unsigned r = x.u + 0x7fffu + ((x.u >> 16) & 1u);   // RNE; inputs are finite
  return (u16)(r >> 16);
}
__device__ __forceinline__ float bf2f(u16 h) {
  union { unsigned u; float f; } x; x.u = ((unsigned)h) << 16;
  return x.f;
}

// async global->LDS, 16 B per lane; LDS dest is wave-uniform base + lane*16
__device__ __forceinline__ void gll16(const u16* g, u16* ldsbase) {
  __builtin_amdgcn_global_load_lds(
      (const __attribute__((address_space(1))) void*)g,
      (__attribute__((address_space(3))) void*)ldsbase, 16, 0, 0);
}

// ---------------------------------------------------------------------------
__global__ __launch_bounds__(256) void f32_to_bf16(const float* __restrict__ in,
                                                   u16* __restrict__ out, size_t n) {
  size_t i = (size_t)blockIdx.x * 256 + threadIdx.x;
  if (i < n) out[i] = f2bf(in[i]);
}

// transpose f32 [R][C] -> bf16 [C][R]   (R,C multiples of 32) grid(C/32, R/32)
__global__ __launch_bounds__(256) void transpose_f32_bf16(const float* __restrict__ in,
                                                          u16* __restrict__ out,
                                                          int R, int C) {
  __shared__ float tile[32][33];
  int c0 = blockIdx.x * 32, r0 = blockIdx.y * 32;
  int tx = threadIdx.x & 31, ty = threadIdx.x >> 5;   // ty: 0..7
  #pragma unroll
  for (int i = ty; i < 32; i += 8)
    tile[i][tx] = in[(size_t)(r0 + i) * C + c0 + tx];
  __syncthreads();
  #pragma unroll
  for (int i = ty; i < 32; i += 8)
    out[(size_t)(c0 + i) * R + r0 + tx] = f2bf(tile[tx][i]);
}

// ---------------------------------------------------------------------------
// Tiled 8-wave GEMM: C[z][M][N] = A[z][M][K] @ Bt[z][N][K]^T, bf16 in, f32 acc.
// BK=64, 512 threads. Three tile configs (grid-fill drove R1: N=1024 shapes at
// BMxBN=256x256 give 128-block grids = half the 256 CUs idle):
//   256x256: 2Mx4N waves, wave 128x64, 4 phases/K-tile (proven R0 path).
//   256x128: 2Mx4N waves, wave 128x32, 2 phases/K-tile, LDS 96 KiB.
//   128x256: 1Mx8N waves, wave 128x32, same 2-phase schedule.
// T2: granule XOR-swizzle (pre-swizzled global src, linear LDS dest, swizzled
//     ds_read_b128) -> 0 bank conflicts (R0 measured).
// T3/T4: region staging via global_load_lds, raw s_barrier, counted vmcnt
//     (never 0 in steady state). T5: setprio(1) around MFMA clusters.
// 2-phase overwrite safety: phase-2 stages (into CURRENT buf, tile t+2) only
// regions whose last read was phase 1 (lgkmcnt(0)+barrier in between);
// phase-1 stages (other buf, t+1) regions last read in tile t-1.
// ---------------------------------------------------------------------------
enum { EPI_F32 = 0, EPI_BF16 = 1, EPI_BF16_SCALE = 2,
       EPI_BIAS_RELU_BF16 = 3, EPI_BIAS_F32 = 4 };
enum { MODE_FULL = 0, MODE_TRI = 1, MODE_CAUSAL_K = 2 };

template <int EPI, int MODE, int BM, int BN>
__global__ __launch_bounds__(512) void gemm256(
    const u16* __restrict__ A, const u16* __restrict__ Bt,
    void* __restrict__ C0, const float* __restrict__ bias,
    int K, int lda, int ldb, int ldc,
    long long sA, long long sB, long long sC)
{
  constexpr int WM  = BM / 128;        // 1 or 2 M-wave groups
  constexpr int WN  = 8 / WM;          // 4 or 8 N-wave groups
  constexpr int CPW = BN / WN;         // cols per wave: 64 or 32
  constexpr int NF  = CPW / 16;        // 4 or 2 n-fragments
  constexpr int nBr = BN / 64;         // B regions (64 rows each)
  constexpr int nAr = BM / 64;         // A regions

  __shared__ __align__(16) u16 lA[2][BM * 64];
  __shared__ __align__(16) u16 lB[2][BN * 64];

  // ---- block -> (z, mi, ni), XCD-compact swizzle (all grids %8==0) ----
  const unsigned gx = gridDim.x, gxy = gridDim.x * gridDim.y;
  unsigned id = blockIdx.x + gx * blockIdx.y + gxy * blockIdx.z;
  const unsigned nb = gxy * gridDim.z;
  unsigned p = id;
  if ((nb & 7u) == 0u) p = (id & 7u) * (nb >> 3) + (id >> 3);
  int z, mi, ni;
  if constexpr (MODE == MODE_TRI) {
    z = (int)(p / gxy);                 // gxy == tri blocks per batch
    int r = (int)(p % gxy);
    int m = 0;
    if constexpr (BN == 256) {          // 1 col-tile per row step
      while ((m + 1) * (m + 2) / 2 <= r) m++;
      mi = m; ni = r - m * (m + 1) / 2;
    } else {                            // BN=128: 2mi+2 col-tiles at row mi
      while ((m + 1) * (m + 2) <= r) m++;
      mi = m; ni = r - m * (m + 1);
    }
  } else {
    z = (int)(p / gxy);
    const unsigned rem = p % gxy;
    mi = (int)(rem / gx);
    ni = (int)(rem % gx);
  }
  const int m0 = mi * BM, n0 = ni * BN;

  A  += (long long)z * sA;
  Bt += (long long)z * sB;

  int NT = K >> 6;
  if constexpr (MODE == MODE_CAUSAL_K) NT = (m0 + BM) >> 6;  // P==0 above diag

  const int t    = threadIdx.x;
  const int lane = t & 63;
  const int wave = t >> 6;
  const int wr   = (WM == 1) ? 0 : (wave >> 2);
  const int wc   = (WM == 1) ? wave : (wave & 3);
  const int quad = lane >> 4;
  const int lrow = lane & 15;

  // ---- staging addressing: pre-swizzled global source, linear LDS dest ----
  const int srow = lane >> 3;                    // 0..7 (== row & 7)
  const int scol = ((lane & 7) ^ srow) * 8;      // source granule for phys lane&7
  const u16* gAp = A  + (size_t)(m0 + wave * 8 + srow) * lda + scol;
  const u16* gBp = Bt + (size_t)(n0 + wave * 8 + srow) * ldb + scol;
  const size_t a64 = (size_t)64 * lda, b64 = (size_t)64 * ldb;
  const int lw = wave * 512;           // wave's write base within a 64-row region

  // ---- fragment read addressing (swizzled): phys granule = need ^ (row&7) ----
  const int pg0 = (quad ^ (lrow & 7)) * 8;       // ks=0
  const int pg1 = pg0 ^ 32;                      // ks=1
  const int rA = (wr * 128 + lrow) * 64;
  const int rB = (wc * CPW + lrow) * 64;

  f32x4 acc[8][NF];
  const f32x4 zero = {0.f, 0.f, 0.f, 0.f};
  #pragma unroll
  for (int i = 0; i < 8; i++)
    #pragma unroll
    for (int j = 0; j < NF; j++) acc[i][j] = zero;

  bf16x8 af[4][2];
  bf16x8 bfr[NF][2];

  if constexpr (BM == 256 && BN == 256) {
    // ======================= 4-phase 256x256 path (R0-proven) ===============
    auto stage = [&](int b, int s, int kt) {
      const int k = kt * 64;
      if (s == 0) {
        gll16(gBp + k,            &lB[b][lw]);
        gll16(gBp + k + b64,      &lB[b][4096 + lw]);
      } else if (s == 1) {
        gll16(gBp + k + 2 * b64,  &lB[b][8192 + lw]);
        gll16(gBp + k + 3 * b64,  &lB[b][12288 + lw]);
      } else if (s == 2) {
        gll16(gAp + k,            &lA[b][lw]);
        gll16(gAp + k + a64,      &lA[b][4096 + lw]);
      } else {
        gll16(gAp + k + 2 * a64,  &lA[b][8192 + lw]);
        gll16(gAp + k + 3 * a64,  &lA[b][12288 + lw]);
      }
    };

    stage(0, 0, 0); stage(0, 1, 0); stage(0, 2, 0); stage(0, 3, 0);
    if (NT > 1) {
      stage(1, 0, 1); stage(1, 1, 1); stage(1, 2, 1);
      asm volatile("s_waitcnt vmcnt(6)" ::: "memory");
    } else {
      asm volatile("s_waitcnt vmcnt(0)" ::: "memory");
    }
    __builtin_amdgcn_s_barrier();

    for (int kt = 0; kt < NT; ++kt) {
      const int bsel = kt & 1;
      const u16* sa = &lA[bsel][0];
      const u16* sb = &lB[bsel][0];

      // phase 1 : Q(0,0)
      #pragma unroll
      for (int mf = 0; mf < 4; ++mf) {
        af[mf][0] = *(const bf16x8*)(sa + rA + mf * 1024 + pg0);
        af[mf][1] = *(const bf16x8*)(sa + rA + mf * 1024 + pg1);
      }
      if (wc < 2) {
        #pragma unroll
        for (int nf = 0; nf < 4; ++nf) {
          bfr[nf][0] = *(const bf16x8*)(sb + rB + nf * 1024 + pg0);
          bfr[nf][1] = *(const bf16x8*)(sb + rB + nf * 1024 + pg1);
        }
      } else {
        #pragma unroll
        for (int nf = 0; nf < 2; ++nf) {
          bfr[nf][0] = *(const bf16x8*)(sb + rB + nf * 1024 + pg0);
          bfr[nf][1] = *(const bf16x8*)(sb + rB + nf * 1024 + pg1);
        }
      }
      if (kt + 1 < NT) stage(bsel ^ 1, 3, kt + 1);
      __builtin_amdgcn_s_barrier();
      asm volatile("s_waitcnt lgkmcnt(0)" ::: "memory");
      __builtin_amdgcn_sched_barrier(0);
      __builtin_amdgcn_s_setprio(1);
      #pragma unroll
      for (int mf = 0; mf < 4; ++mf)
        #pragma unroll
        for (int nf = 0; nf < 2; ++nf) {
          acc[mf][nf] = __builtin_amdgcn_mfma_f32_16x16x32_bf16(bfr[nf][0], af[mf][0], acc[mf][nf], 0, 0, 0);
          acc[mf][nf] = __builtin_amdgcn_mfma_f32_16x16x32_bf16(bfr[nf][1], af[mf][1], acc[mf][nf], 0, 0, 0);
        }
      __builtin_amdgcn_s_setprio(0);
      __builtin_amdgcn_s_barrier();

      // phase 2 : Q(0,1)
      if (wc >= 2) {
        #pragma unroll
        for (int nf = 2; nf < 4; ++nf) {
          bfr[nf][0] = *(const bf16x8*)(sb + rB + nf * 1024 + pg0);
          bfr[nf][1] = *(const bf16x8*)(sb + rB + nf * 1024 + pg1);
        }
      }
      if (kt + 2 < NT) stage(bsel, 0, kt + 2);
      __builtin_amdgcn_s_barrier();
      asm volatile("s_waitcnt lgkmcnt(0)" ::: "memory");
      __builtin_amdgcn_sched_barrier(0);
      __builtin_amdgcn_s_setprio(1);
      #pragma unroll
      for (int mf = 0; mf < 4; ++mf)
        #pragma unroll
        for (int nf = 2; nf < 4; ++nf) {
          acc[mf][nf] = __builtin_amdgcn_mfma_f32_16x16x32_bf16(bfr[nf][0], af[mf][0], acc[mf][nf], 0, 0, 0);
          acc[mf][nf] = __builtin_amdgcn_mfma_f32_16x16x32_bf16(bfr[nf][1], af[mf][1], acc[mf][nf], 0, 0, 0);
        }
      __builtin_amdgcn_s_setprio(0);
      __builtin_amdgcn_s_barrier();

      // phase 3 : Q(1,1)
      #pragma unroll
      for (int mf = 0; mf < 4; ++mf) {
        af[mf][0] = *(const bf16x8*)(sa + rA + (mf + 4) * 1024 + pg0);
        af[mf][1] = *(const bf16x8*)(sa + rA + (mf + 4) * 1024 + pg1);
      }
      if (kt + 2 < NT) stage(bsel, 1, kt + 2);
      __builtin_amdgcn_s_barrier();
      asm volatile("s_waitcnt lgkmcnt(0)" ::: "memory");
      __builtin_amdgcn_sched_barrier(0);
      __builtin_amdgcn_s_setprio(1);
      #pragma unroll
      for (int mf = 0; mf < 4; ++mf)
        #pragma unroll
        for (int nf = 2; nf < 4; ++nf) {
          acc[mf + 4][nf] = __builtin_amdgcn_mfma_f32_16x16x32_bf16(bfr[nf][0], af[mf][0], acc[mf + 4][nf], 0, 0, 0);
          acc[mf + 4][nf] = __builtin_amdgcn_mfma_f32_16x16x32_bf16(bfr[nf][1], af[mf][1], acc[mf + 4][nf], 0, 0, 0);
        }
      __builtin_amdgcn_s_setprio(0);
      __builtin_amdgcn_s_barrier();

      // phase 4 : Q(1,0)
      if (kt + 2 < NT) {
        stage(bsel, 2, kt + 2);
        asm volatile("s_waitcnt vmcnt(6)" ::: "memory");
      } else if (kt + 1 < NT) {
        asm volatile("s_waitcnt vmcnt(0)" ::: "memory");
      }
      __builtin_amdgcn_s_barrier();
      __builtin_amdgcn_s_setprio(1);
      #pragma unroll
      for (int mf = 0; mf < 4; ++mf)
        #pragma unroll
        for (int nf = 0; nf < 2; ++nf) {
          acc[mf + 4][nf] = __builtin_amdgcn_mfma_f32_16x16x32_bf16(bfr[nf][0], af[mf][0], acc[mf + 4][nf], 0, 0, 0);
          acc[mf + 4][nf] = __builtin_amdgcn_mfma_f32_16x16x32_bf16(bfr[nf][1], af[mf][1], acc[mf + 4][nf], 0, 0, 0);
        }
      __builtin_amdgcn_s_setprio(0);
      __builtin_amdgcn_s_barrier();
    }
  } else {
    // ======================= 2-phase narrow-tile path =======================
    // 6 regions (64 rows x 64 cols, 8 KB): 0..nBr-1 = B, nBr..5 = A.
    // half 0 = regions {0,1,2} (all read in phase 1); half 1 = {3,4,5}.
    auto stage3 = [&](int b, int h, int kt) {
      const int k = kt * 64;
      #pragma unroll
      for (int s = 0; s < 3; ++s) {
        const int rg = h * 3 + s;
        if (rg < nBr) gll16(gBp + k + (size_t)rg * b64, &lB[b][rg * 4096 + lw]);
        else          gll16(gAp + k + (size_t)(rg - nBr) * a64, &lA[b][(rg - nBr) * 4096 + lw]);
      }
    };

    stage3(0, 0, 0); stage3(0, 1, 0);
    if (NT > 1) {
      stage3(1, 0, 1);
      asm volatile("s_waitcnt vmcnt(3)" ::: "memory");   // tile0's 6 loads landed
    } else {
      asm volatile("s_waitcnt vmcnt(0)" ::: "memory");
    }
    __builtin_amdgcn_s_barrier();

    for (int kt = 0; kt < NT; ++kt) {
      const int bsel = kt & 1;
      const u16* sa = &lA[bsel][0];
      const u16* sb = &lB[bsel][0];

      // phase 1 : mf 0..3  (reads A rows wr*128..+63 and all of this wave's B)
      #pragma unroll
      for (int mf = 0; mf < 4; ++mf) {
        af[mf][0] = *(const bf16x8*)(sa + rA + mf * 1024 + pg0);
        af[mf][1] = *(const bf16x8*)(sa + rA + mf * 1024 + pg1);
      }
      #pragma unroll
      for (int nf = 0; nf < 2; ++nf) {
        bfr[nf][0] = *(const bf16x8*)(sb + rB + nf * 1024 + pg0);
        bfr[nf][1] = *(const bf16x8*)(sb + rB + nf * 1024 + pg1);
      }
      if (kt + 1 < NT) stage3(bsel ^ 1, 1, kt + 1);
      __builtin_amdgcn_s_barrier();
      asm volatile("s_waitcnt lgkmcnt(0)" ::: "memory");
      __builtin_amdgcn_sched_barrier(0);
      __builtin_amdgcn_s_setprio(1);
      #pragma unroll
      for (int mf = 0; mf < 4; ++mf)
        #pragma unroll
        for (int nf = 0; nf < 2; ++nf) {
          acc[mf][nf] = __builtin_amdgcn_mfma_f32_16x16x32_bf16(bfr[nf][0], af[mf][0], acc[mf][nf], 0, 0, 0);
          acc[mf][nf] = __builtin_amdgcn_mfma_f32_16x16x32_bf16(bfr[nf][1], af[mf][1], acc[mf][nf], 0, 0, 0);
        }
      __builtin_amdgcn_s_setprio(0);
      __builtin_amdgcn_s_barrier();

      // phase 2 : mf 4..7  (reads A rows wr*128+64..+127)
      #pragma unroll
      for (int mf = 0; mf < 4; ++mf) {
        af[mf][0] = *(const bf16x8*)(sa + rA + (mf + 4) * 1024 + pg0);
        af[mf][1] = *(const bf16x8*)(sa + rA + (mf + 4) * 1024 + pg1);
      }
      if (kt + 2 < NT) {
        stage3(bsel, 0, kt + 2);
        asm volatile("s_waitcnt vmcnt(3)" ::: "memory");  // tile kt+1 fully landed
      } else if (kt + 1 < NT) {
        asm volatile("s_waitcnt vmcnt(0)" ::: "memory");
      }
      __builtin_amdgcn_s_barrier();
      asm volatile("s_waitcnt lgkmcnt(0)" ::: "memory");
      __builtin_amdgcn_sched_barrier(0);
      __builtin_amdgcn_s_setprio(1);
      #pragma unroll
      for (int mf = 0; mf < 4; ++mf)
        #pragma unroll
        for (int nf = 0; nf < 2; ++nf) {
          acc[mf + 4][nf] = __builtin_amdgcn_mfma_f32_16x16x32_bf16(bfr[nf][0], af[mf][0], acc[mf + 4][nf], 0, 0, 0);
          acc[mf + 4][nf] = __builtin_amdgcn_mfma_f32_16x16x32_bf16(bfr[nf][1], af[mf][1], acc[mf + 4][nf], 0, 0, 0);
        }
      __builtin_amdgcn_s_setprio(0);
      __builtin_amdgcn_s_barrier();
    }
  }

  // ---- epilogue: swapped C/D layout -> lane holds 4 consecutive n ----
  const size_t zoff = (size_t)((long long)z * sC);
  #pragma unroll
  for (int mf = 0; mf < 8; ++mf) {
    #pragma unroll
    for (int nf = 0; nf < NF; ++nf) {
      const size_t m  = (size_t)(m0 + wr * 128 + mf * 16 + lrow);
      const size_t nc = (size_t)(n0 + wc * CPW + nf * 16 + quad * 4);
      const size_t idx = zoff + m * (size_t)ldc + nc;
      f32x4 v = acc[mf][nf];
      if constexpr (EPI == EPI_F32) {
        *(float4*)((float*)C0 + idx) = make_float4(v[0], v[1], v[2], v[3]);
      } else if constexpr (EPI == EPI_BF16) {
        ushort4 o; o.x = f2bf(v[0]); o.y = f2bf(v[1]); o.z = f2bf(v[2]); o.w = f2bf(v[3]);
        *(ushort4*)((u16*)C0 + idx) = o;
      } else if constexpr (EPI == EPI_BF16_SCALE) {
        ushort4 o;
        o.x = f2bf(v[0] * 0.03125f); o.y = f2bf(v[1] * 0.03125f);
        o.z = f2bf(v[2] * 0.03125f); o.w = f2bf(v[3] * 0.03125f);
        *(ushort4*)((u16*)C0 + idx) = o;
      } else if constexpr (EPI == EPI_BIAS_RELU_BF16) {
        const float4 bb = *(const float4*)(bias + nc);
        float y0 = v[0] + bb.x, y1 = v[1] + bb.y, y2 = v[2] + bb.z, y3 = v[3] + bb.w;
        ushort4 o;
        o.x = f2bf(y0 > 0.f ? y0 : 0.f); o.y = f2bf(y1 > 0.f ? y1 : 0.f);
        o.z = f2bf(y2 > 0.f ? y2 : 0.f); o.w = f2bf(y3 > 0.f ? y3 : 0.f);
        *(ushort4*)((u16*)C0 + idx) = o;
      } else {  // EPI_BIAS_F32
        const float4 bb = *(const float4*)(bias + nc);
        *(float4*)((float*)C0 + idx) =
            make_float4(v[0] + bb.x, v[1] + bb.y, v[2] + bb.z, v[3] + bb.w);
      }
    }
  }
}

// ---------------------------------------------------------------------------
// in-place row softmax on bf16 scores (already scaled); cols == 2048.
// Causal: skips loads past q and stores past the 256-aligned diagonal tile
// boundary (cols >= wlimit are never written by TRI nor read by clamped PV).
// ---------------------------------------------------------------------------
__global__ __launch_bounds__(256) void softmax_bf16(u16* __restrict__ SP, int causal) {
  __shared__ float red[8];
  const int row = blockIdx.x;
  const int q = row & 2047;
  u16* p = SP + (size_t)row * 2048;
  const int t = threadIdx.x;
  const int base = t * 8;
  const int limit  = causal ? (q + 1) : 2048;
  const int wlimit = causal ? (((q >> 8) + 1) << 8) : 2048;

  float v[8];
  if (base < limit) {
    uint4 raw = *(const uint4*)(p + base);
    unsigned w[4] = {raw.x, raw.y, raw.z, raw.w};
    #pragma unroll
    for (int j = 0; j < 4; j++) {
      union { unsigned u; float f; } lo, hi;
      lo.u = w[j] << 16; hi.u = w[j] & 0xffff0000u;
      v[2 * j] = lo.f; v[2 * j + 1] = hi.f;
    }
    #pragma unroll
    for (int j = 0; j < 8; j++) if (base + j >= limit) v[j] = -3.4e38f;
  } else {
    #pragma unroll
    for (int j = 0; j < 8; j++) v[j] = -3.4e38f;
  }

  float mx = v[0];
  #pragma unroll
  for (int j = 1; j < 8; j++) mx = fmaxf(mx, v[j]);
  #pragma unroll
  for (int o = 32; o > 0; o >>= 1) mx = fmaxf(mx, __shfl_down(mx, o));
  if ((t & 63) == 0) red[t >> 6] = mx;
  __syncthreads();
  mx = fmaxf(fmaxf(red[0], red[1]), fmaxf(red[2], red[3]));

  float s = 0.f;
  #pragma unroll
  for (int j = 0; j < 8; j++) { float e = __expf(v[j] - mx); v[j] = e; s += e; }
  #pragma unroll
  for (int o = 32; o > 0; o >>= 1) s += __shfl_down(s, o);
  if ((t & 63) == 0) red[4 + (t >> 6)] = s;
  __syncthreads();
  const float inv = 1.f / (red[4] + red[5] + red[6] + red[7]);

  if (base < wlimit) {
    unsigned o4[4];
    #pragma unroll
    for (int j = 0; j < 4; j++)
      o4[j] = (unsigned)f2bf(v[2 * j] * inv) | ((unsigned)f2bf(v[2 * j + 1] * inv) << 16);
    *(uint4*)(p + base) = make_uint4(o4[0], o4[1], o4[2], o4[3]);
  }
}

// ---------------------------------------------------------------------------
// LN(a + b) * g + be ; D == 1024; a bf16 (ABF=1) or f32 (ABF=0)
// ---------------------------------------------------------------------------
template <int ABF>
__global__ __launch_bounds__(256) void ln_residual(const void* __restrict__ a_,
                                                   const float* __restrict__ b,
                                                   const float* __restrict__ g,
                                                   const float* __restrict__ be,
                                                   float* __restrict__ outf,
                                                   u16* __restrict__ outb) {
  __shared__ float red[8];
  const size_t base = (size_t)blockIdx.x * 1024;
  const int t = threadIdx.x;
  const int i0 = t * 4;

  float va[4];
  if constexpr (ABF) {
    const ushort4 h = *(const ushort4*)((const u16*)a_ + base + i0);
    va[0] = bf2f(h.x); va[1] = bf2f(h.y); va[2] = bf2f(h.z); va[3] = bf2f(h.w);
  } else {
    const float4 f = *(const float4*)((const float*)a_ + base + i0);
    va[0] = f.x; va[1] = f.y; va[2] = f.z; va[3] = f.w;
  }
  const float4 vb = *(const float4*)(b + base + i0);
  float v[4] = {va[0] + vb.x, va[1] + vb.y, va[2] + vb.z, va[3] + vb.w};

  float s = v[0] + v[1] + v[2] + v[3];
  #pragma unroll
  for (int o = 32; o > 0; o >>= 1) s += __shfl_down(s, o);
  if ((t & 63) == 0) red[t >> 6] = s;
  __syncthreads();
  const float mean = (red[0] + red[1] + red[2] + red[3]) * (1.f / 1024.f);

  float qq = 0.f;
  #pragma unroll
  for (int i = 0; i < 4; i++) { float d = v[i] - mean; qq += d * d; }
  #pragma unroll
  for (int o = 32; o > 0; o >>= 1) qq += __shfl_down(qq, o);
  if ((t & 63) == 0) red[4 + (t >> 6)] = qq;
  __syncthreads();
  const float rstd = rsqrtf((red[4] + red[5] + red[6] + red[7]) * (1.f / 1024.f) + 1e-5f);

  const float4 gg = *(const float4*)(g + i0);
  const float4 bb = *(const float4*)(be + i0);
  float y0 = (v[0] - mean) * rstd * gg.x + bb.x;
  float y1 = (v[1] - mean) * rstd * gg.y + bb.y;
  float y2 = (v[2] - mean) * rstd * gg.z + bb.z;
  float y3 = (v[3] - mean) * rstd * gg.w + bb.w;
  if (outf) *(float4*)(outf + base + i0) = make_float4(y0, y1, y2, y3);
  if (outb) {
    ushort4 o4; o4.x = f2bf(y0); o4.y = f2bf(y1); o4.z = f2bf(y2); o4.w = f2bf(y3);
    *(ushort4*)(outb + base + i0) = o4;
  }
}

// ---------------------------------------------------------------------------
extern "C" void kernel_launch(void* const* d_in, const int* in_sizes, int n_in,
                              void* d_out, int out_size, void* d_ws, size_t ws_size,
                              hipStream_t stream)
{
  const float* y_in = (const float*)d_in[0];
  const float* Z_in = (const float*)d_in[1];
  const float* WQ1  = (const float*)d_in[2];
  const float* WK1  = (const float*)d_in[3];
  const float* WV1  = (const float*)d_in[4];
  const float* WQ2  = (const float*)d_in[5];
  const float* WK2  = (const float*)d_in[6];
  const float* WV2  = (const float*)d_in[7];
  const float* Wff1 = (const float*)d_in[8];
  const float* bff1 = (const float*)d_in[9];
  const float* Wff2 = (const float*)d_in[10];
  const float* bff2 = (const float*)d_in[11];
  const float* g1  = (const float*)d_in[12];
  const float* be1 = (const float*)d_in[13];
  const float* g2  = (const float*)d_in[14];
  const float* be2 = (const float*)d_in[15];
  const float* g3  = (const float*)d_in[16];
  const float* be3 = (const float*)d_in[17];
  (void)in_sizes; (void)n_in; (void)out_size;

  constexpr int Bn = 4, S = 2048, D = 1024, DF = 4096;
  constexpr long long BS = (long long)Bn * S;  // 8192 rows
  const long long SD = (long long)S * D;                 // 2M
  const long long SS = (long long)S * S;                 // 4M
  const long long SD2 = (long long)S * 2 * D;            // 4M: QKb batch stride

  char* ws = (char*)d_ws;
  size_t off = 0;
  auto alloc = [&](size_t bytes) -> char* {
    char* p = ws + off;
    off += (bytes + 255) & ~(size_t)255;
    return p;
  };

  // ---- workspace. NOTE: wq1t..wk1t must stay contiguous (merged Q|K weight
  // view for stage 1) — sizes are multiples of 256 B.
  u16* wq1t  = (u16*)alloc((size_t)D * D * 2);
  u16* wk1t  = (u16*)alloc((size_t)D * D * 2);
  u16* wv1t  = (u16*)alloc((size_t)D * D * 2);
  u16* wq2t  = (u16*)alloc((size_t)D * D * 2);
  u16* wk2t  = (u16*)alloc((size_t)D * D * 2);
  u16* wv2t  = (u16*)alloc((size_t)D * D * 2);
  u16* wff1t = (u16*)alloc((size_t)D * DF * 2);   // [4096][1024]
  u16* wff2t = (u16*)alloc((size_t)D * DF * 2);   // [1024][4096]
  u16* ybf   = (u16*)alloc((size_t)BS * D * 2);   // X1; reused as y1b after LN1
  u16* zbf   = (u16*)alloc((size_t)BS * D * 2);   // Z;  reused as y2b after LN2
  u16* QKb   = (u16*)alloc((size_t)BS * 2 * D * 2); // [8192][2048]: Q | K
  u16* Vtb   = (u16*)alloc((size_t)D * BS * 2);   // [1024][8192]: V^T, batch = col window
  u16* SPb   = (u16*)alloc((size_t)Bn * S * S * 2); // scores/probs bf16, in-place
  float* attnF = (float*)alloc((size_t)BS * D * 4); // attn out f32; reused as F
  u16*   y1b = ybf;
  u16*   y2b = zbf;
  u16*   Hb  = QKb;      // stage-3 hidden [8192][4096] overlays QKb|Vtb|SPb (dead)
  float* Fb  = attnF;

  if (off > ws_size) return;   // fail cleanly (absmax) instead of GPU fault

  const dim3 blk(256);
  const dim3 blk512(512);

  // ---- input converts + weight transposes ----
  f32_to_bf16<<<dim3((unsigned)((BS * D) / 256)), blk, 0, stream>>>(y_in, ybf, (size_t)BS * D);
  f32_to_bf16<<<dim3((unsigned)((BS * D) / 256)), blk, 0, stream>>>(Z_in, zbf, (size_t)BS * D);
  transpose_f32_bf16<<<dim3(D / 32, D / 32), blk, 0, stream>>>(WQ1, wq1t, D, D);
  transpose_f32_bf16<<<dim3(D / 32, D / 32), blk, 0, stream>>>(WK1, wk1t, D, D);
  transpose_f32_bf16<<<dim3(D / 32, D / 32), blk, 0, stream>>>(WV1, wv1t, D, D);
  transpose_f32_bf16<<<dim3(D / 32, D / 32), blk, 0, stream>>>(WQ2, wq2t, D, D);
  transpose_f32_bf16<<<dim3(D / 32, D / 32), blk, 0, stream>>>(WK2, wk2t, D, D);
  transpose_f32_bf16<<<dim3(D / 32, D / 32), blk, 0, stream>>>(WV2, wv2t, D, D);
  transpose_f32_bf16<<<dim3(DF / 32, D / 32), blk, 0, stream>>>(Wff1, wff1t, D, DF);
  transpose_f32_bf16<<<dim3(D / 32, DF / 32), blk, 0, stream>>>(Wff2, wff2t, DF, D);

  // ---- stage 1: causal self-attention + add&norm ----
  // Q|K projection: merged WQ^T||WK^T view (contiguous), C = QKb [8192][2048]
  gemm256<EPI_BF16, MODE_FULL, 256, 256><<<dim3(2 * D / 256, BS / 256, 1), blk512, 0, stream>>>(
      ybf, wq1t, QKb, nullptr, D, D, D, 2 * D, 0, 0, 0);
  // V^T: Vt[d][s] = sum_k WvT[d][k] * X[s][k]  -> C [1024][8192]  (128x256: 256 blocks)
  gemm256<EPI_BF16, MODE_FULL, 128, 256><<<dim3((unsigned)(BS / 256), D / 128, 1), blk512, 0, stream>>>(
      wv1t, ybf, Vtb, nullptr, D, D, D, (int)BS, 0, 0, 0);
  // causal scores: lower-triangle 256x128 tiles (72/batch -> 288 blocks)
  gemm256<EPI_BF16_SCALE, MODE_TRI, 256, 128><<<dim3(72, 1, Bn), blk512, 0, stream>>>(
      QKb, QKb + D, SPb, nullptr, D, 2 * D, 2 * D, S, SD2, SD2, SS);
  softmax_bf16<<<dim3((unsigned)(Bn * S)), blk, 0, stream>>>(SPb, 1);
  // PV: K-loop clamped to diagonal (P == 0 above it)  (256x128: 256 blocks)
  gemm256<EPI_F32, MODE_CAUSAL_K, 256, 128><<<dim3(D / 128, S / 256, Bn), blk512, 0, stream>>>(
      SPb, Vtb, attnF, nullptr, S, S, (int)BS, D, SS, S, SD);
  ln_residual<0><<<dim3((unsigned)BS), blk, 0, stream>>>(y_in, attnF, g1, be1, nullptr, y1b);

  // ---- stage 2: cross-attention + add&norm ----
  gemm256<EPI_BF16, MODE_FULL, 256, 128><<<dim3(D / 128, BS / 256, 1), blk512, 0, stream>>>(
      y1b, wq2t, QKb, nullptr, D, D, D, 2 * D, 0, 0, 0);
  gemm256<EPI_BF16, MODE_FULL, 256, 128><<<dim3(D / 128, BS / 256, 1), blk512, 0, stream>>>(
      zbf, wk2t, QKb + D, nullptr, D, D, D, 2 * D, 0, 0, 0);
  gemm256<EPI_BF16, MODE_FULL, 128, 256><<<dim3((unsigned)(BS / 256), D / 128, 1), blk512, 0, stream>>>(
      wv2t, zbf, Vtb, nullptr, D, D, D, (int)BS, 0, 0, 0);
  gemm256<EPI_BF16_SCALE, MODE_FULL, 256, 256><<<dim3(S / 256, S / 256, Bn), blk512, 0, stream>>>(
      QKb, QKb + D, SPb, nullptr, D, 2 * D, 2 * D, S, SD2, SD2, SS);
  softmax_bf16<<<dim3((unsigned)(Bn * S)), blk, 0, stream>>>(SPb, 0);
  gemm256<EPI_F32, MODE_FULL, 256, 128><<<dim3(D / 128, S / 256, Bn), blk512, 0, stream>>>(
      SPb, Vtb, attnF, nullptr, S, S, (int)BS, D, SS, S, SD);
  ln_residual<1><<<dim3((unsigned)BS), blk, 0, stream>>>(y1b, attnF, g2, be2, nullptr, y2b);

  // ---- stage 3: FFN + add&norm ----
  gemm256<EPI_BIAS_RELU_BF16, MODE_FULL, 256, 256><<<dim3(DF / 256, BS / 256, 1), blk512, 0, stream>>>(
      y2b, wff1t, Hb, bff1, D, D, D, DF, 0, 0, 0);
  gemm256<EPI_BIAS_F32, MODE_FULL, 256, 128><<<dim3(D / 128, BS / 256, 1), blk512, 0, stream>>>(
      Hb, wff2t, Fb, bff2, DF, DF, DF, D, 0, 0, 0);
  ln_residual<1><<<dim3((unsigned)BS), blk, 0, stream>>>(y2b, Fb, g3, be3, (float*)d_out, nullptr);
}